// Round 11
// baseline (131.403 us; speedup 1.0000x reference)
//
#include <hip/hip_runtime.h>
#include <hip/hip_bf16.h>

typedef __attribute__((ext_vector_type(8))) short short8;
typedef __attribute__((ext_vector_type(4))) float f32x4;

static constexpr int S_ = 256;
static constexpr int D_ = 64;
// softmax scale * log2(e): GEMM directly produces log2-domain scores
static constexpr float QSCALE = 0.125f * 1.44269504088896340736f;

__device__ __forceinline__ unsigned cvt_pk_bf16(float lo, float hi) {
    unsigned r;
    asm("v_cvt_pk_bf16_f32 %0, %1, %2" : "=v"(r) : "v"(lo), "v"(hi));
    return r;
}

// 256 threads = 4 waves; wave w owns i-quarter [w*64, w*64+64) for BOTH queries.
// Each K2 B-fragment feeds 8 MFMAs (2 i-tiles x 2 q) -> LDS read traffic halved vs R10.
__global__ __launch_bounds__(256, 2) void tritt_fused(
    const float* __restrict__ qg, const float* __restrict__ k1g,
    const float* __restrict__ k2g, const float* __restrict__ v1g,
    const float* __restrict__ v2g, float* __restrict__ outg)
{
    __shared__ unsigned short sK2[S_ * D_];  // 32 KB, bf16 XOR-swizzled
    __shared__ float sPi[2][S_];             // 2 KB  (per-query pi)
    __shared__ float sPjH[4][2][S_];         // 8 KB  (per-wave pj partials, per q)

    const int tid = threadIdx.x;
    const int qt = blockIdx.x & 127;         // 128 q-tiles of 2
    const int h  = blockIdx.x >> 7;
    const int q0 = qt * 2;

    const float* K1h = k1g + h * (S_ * D_);
    const float* K2h = k2g + h * (S_ * D_);

    // ---- stage K2 (full) as swizzled bf16 ----
    #pragma unroll
    for (int it = 0; it < 16; ++it) {
        const int e4  = tid * 4 + it * 1024;
        const int row = e4 >> 6, d = e4 & 63;
        const int idx = row * 64 + (d ^ ((row & 7) << 3));
        const float4 b = *(const float4*)(K2h + e4);
        uint2 pb; pb.x = cvt_pk_bf16(b.x, b.y); pb.y = cvt_pk_bf16(b.z, b.w);
        *(uint2*)&sK2[idx] = pb;
    }

    const int w   = tid >> 6;
    const int l   = tid & 63;
    const int g   = l >> 4;      // 16-lane group (k-slice g*8..g*8+7)
    const int sub = l & 15;
    // row % 8 == sub % 8 for every j-tile row this lane touches -> swizzled
    // column is a per-lane CONSTANT; all tile addresses are base + immediate.
    const int cb0 = (g * 8) ^ ((sub & 7) << 3);
    const int cb1 = (32 + g * 8) ^ ((sub & 7) << 3);
    const int jb  = sub * 64;

    // Q fragments for both queries (pre-scaled), from global
    float qs[2][2][8];
    #pragma unroll
    for (int q = 0; q < 2; ++q) {
        const float* Qrow = qg + (h * S_ + q0 + q) * D_;
        #pragma unroll
        for (int k = 0; k < 2; ++k) {
            const f32x4 a = *(const f32x4*)(Qrow + k * 32 + g * 8);
            const f32x4 b = *(const f32x4*)(Qrow + k * 32 + g * 8 + 4);
            #pragma unroll
            for (int e = 0; e < 4; ++e) {
                qs[q][k][e]     = a[e] * QSCALE;
                qs[q][k][4 + e] = b[e] * QSCALE;
            }
        }
    }
    __syncthreads();

    float pjreg[2][16];
    #pragma unroll
    for (int q = 0; q < 2; ++q)
        #pragma unroll
        for (int a = 0; a < 16; ++a) pjreg[q][a] = 0.f;

    // ---- 2 passes of (2 i-tiles x 2 queries) x full j (256) ----
    for (int pass = 0; pass < 2; ++pass) {
        // A fragments: one K1 read serves both queries
        short8 af[2][2][2];   // [t][q][k]
        #pragma unroll
        for (int t = 0; t < 2; ++t) {
            const int arow = w * 64 + pass * 32 + t * 16 + sub;
            #pragma unroll
            for (int k = 0; k < 2; ++k) {
                const f32x4 a = *(const f32x4*)(K1h + arow * 64 + k * 32 + g * 8);
                const f32x4 b = *(const f32x4*)(K1h + arow * 64 + k * 32 + g * 8 + 4);
                #pragma unroll
                for (int q = 0; q < 2; ++q) {
                    union { unsigned u[4]; short8 s; } pk;
                    pk.u[0] = cvt_pk_bf16(a[0] * qs[q][k][0], a[1] * qs[q][k][1]);
                    pk.u[1] = cvt_pk_bf16(a[2] * qs[q][k][2], a[3] * qs[q][k][3]);
                    pk.u[2] = cvt_pk_bf16(b[0] * qs[q][k][4], b[1] * qs[q][k][5]);
                    pk.u[3] = cvt_pk_bf16(b[2] * qs[q][k][6], b[3] * qs[q][k][7]);
                    af[t][q][k] = pk.s;
                }
            }
        }

        float pireg[2][2][4];   // [t][q][r]
        #pragma unroll
        for (int t = 0; t < 2; ++t)
            #pragma unroll
            for (int q = 0; q < 2; ++q)
                #pragma unroll
                for (int r = 0; r < 4; ++r) pireg[t][q][r] = 0.f;

        #pragma unroll
        for (int jc = 0; jc < 4; ++jc) {
            #pragma unroll
            for (int jt = 0; jt < 4; ++jt) {
                const int e0 = jb + jc * 4096 + jt * 1024;   // + const col -> imm offsets
                const short8 b0 = *(const short8*)&sK2[e0 + cb0];
                const short8 b1 = *(const short8*)&sK2[e0 + cb1];
                f32x4 acc[2][2];
                #pragma unroll
                for (int t = 0; t < 2; ++t)
                    #pragma unroll
                    for (int q = 0; q < 2; ++q)
                        acc[t][q] = __builtin_amdgcn_mfma_f32_16x16x32_bf16(af[t][q][0], b0, (f32x4){0.f,0.f,0.f,0.f}, 0, 0, 0);
                #pragma unroll
                for (int t = 0; t < 2; ++t)
                    #pragma unroll
                    for (int q = 0; q < 2; ++q)
                        acc[t][q] = __builtin_amdgcn_mfma_f32_16x16x32_bf16(af[t][q][1], b1, acc[t][q], 0, 0, 0);
                // p = 2^t ; pi independent adds, pj 3-level tree per q
                float e_[2][2][4];
                #pragma unroll
                for (int t = 0; t < 2; ++t)
                    #pragma unroll
                    for (int q = 0; q < 2; ++q)
                        #pragma unroll
                        for (int r = 0; r < 4; ++r) {
                            e_[t][q][r] = __builtin_amdgcn_exp2f(acc[t][q][r]);
                            pireg[t][q][r] += e_[t][q][r];  // i = w*64+pass*32+t*16+g*4+r
                        }
                #pragma unroll
                for (int q = 0; q < 2; ++q) {
                    const float s0 = (e_[0][q][0] + e_[0][q][1]) + (e_[0][q][2] + e_[0][q][3]);
                    const float s1 = (e_[1][q][0] + e_[1][q][1]) + (e_[1][q][2] + e_[1][q][3]);
                    pjreg[q][jc * 4 + jt] += s0 + s1;       // j = (jc*4+jt)*16 + sub
                }
            }
        }

        // flush pi (reduce over 16 sub lanes = distinct j)
        #pragma unroll
        for (int t = 0; t < 2; ++t)
            #pragma unroll
            for (int q = 0; q < 2; ++q)
                #pragma unroll
                for (int r = 0; r < 4; ++r) {
                    float v = pireg[t][q][r];
                    v += __shfl_xor(v, 1); v += __shfl_xor(v, 2);
                    v += __shfl_xor(v, 4); v += __shfl_xor(v, 8);
                    if (sub == 0) sPi[q][w * 64 + pass * 32 + t * 16 + g * 4 + r] = v;
                }
    }

    // pj partials: reduce over the 4 lane-groups (distinct i) -> per-wave strips
    #pragma unroll
    for (int q = 0; q < 2; ++q)
        #pragma unroll
        for (int jj = 0; jj < 16; ++jj) {
            float v = pjreg[q][jj];
            v += __shfl_xor(v, 16); v += __shfl_xor(v, 32);
            if (l < 16) sPjH[w][q][jj * 16 + l] = v;
        }
    __syncthreads();   // main phase done; sK2 now dead

    // combine the 4 per-wave pj partials into sPjH[0]
    if (tid < 128) {
        const int q  = tid >> 6;
        const int j4 = (tid & 63) * 4;
        f32x4 s = *(const f32x4*)&sPjH[0][q][j4];
        s += *(const f32x4*)&sPjH[1][q][j4];
        s += *(const f32x4*)&sPjH[2][q][j4];
        s += *(const f32x4*)&sPjH[3][q][j4];
        *(f32x4*)&sPjH[0][q][j4] = s;
    }
    __syncthreads();

    // ---- cooperative epilogue: wave w covers rows [w*64, w*64+64) for both q ----
    float* sTmp = (float*)sK2;   // carved from dead sK2
    {
        const int d = l;
        const float* V1h = v1g + h * (S_ * D_);
        const float* V2h = v2g + h * (S_ * D_);
        float p0 = 0.f, p1 = 0.f;
        #pragma unroll 4
        for (int rb = 0; rb < 16; ++rb) {
            const int r0 = w * 64 + rb * 4;
            const f32x4 pi0 = *(const f32x4*)&sPi[0][r0];
            const f32x4 pi1 = *(const f32x4*)&sPi[1][r0];
            const f32x4 pj0 = *(const f32x4*)&sPjH[0][0][r0];
            const f32x4 pj1 = *(const f32x4*)&sPjH[0][1][r0];
            #pragma unroll
            for (int e = 0; e < 4; ++e) {
                const float v1 = V1h[(r0 + e) * D_ + d];
                const float v2 = V2h[(r0 + e) * D_ + d];
                p0 += pi0[e] * v1 + pj0[e] * v2;
                p1 += pi1[e] * v1 + pj1[e] * v2;
            }
        }
        sTmp[w * 128 + 0 * 64 + d] = p0;
        sTmp[w * 128 + 1 * 64 + d] = p1;
    }
    __syncthreads();
    if (tid < 128) {
        const int qq = tid >> 6, d = tid & 63;
        const float oo = sTmp[0 * 128 + qq * 64 + d] + sTmp[1 * 128 + qq * 64 + d]
                       + sTmp[2 * 128 + qq * 64 + d] + sTmp[3 * 128 + qq * 64 + d];
        float ls = sPi[qq][d] + sPi[qq][64 + d] + sPi[qq][128 + d] + sPi[qq][192 + d];
        ls += __shfl_xor(ls, 1);  ls += __shfl_xor(ls, 2);  ls += __shfl_xor(ls, 4);
        ls += __shfl_xor(ls, 8);  ls += __shfl_xor(ls, 16); ls += __shfl_xor(ls, 32);
        outg[(h * S_ + q0 + qq) * D_ + d] = oo / ls;
        if (d == 0)
            outg[8 * S_ * D_ + h * S_ + q0 + qq] = logf(ls);
    }
}

extern "C" void kernel_launch(void* const* d_in, const int* in_sizes, int n_in,
                              void* d_out, int out_size, void* d_ws, size_t ws_size,
                              hipStream_t stream) {
    const float* q  = (const float*)d_in[0];
    const float* k1 = (const float*)d_in[1];
    const float* k2 = (const float*)d_in[2];
    const float* v1 = (const float*)d_in[3];
    const float* v2 = (const float*)d_in[4];
    float* out = (float*)d_out;
    tritt_fused<<<dim3(8 * (S_ / 2)), dim3(256), 0, stream>>>(q, k1, k2, v1, v2, out);
}

// Round 12
// 50.376 us; speedup vs baseline: 2.6085x; 2.6085x over previous
//
#include <hip/hip_runtime.h>
#include <hip/hip_bf16.h>

typedef __attribute__((ext_vector_type(8))) short short8;
typedef __attribute__((ext_vector_type(4))) float f32x4;
typedef __attribute__((ext_vector_type(2))) float f32x2;

static constexpr int S_ = 256;
static constexpr int D_ = 64;
// softmax scale * log2(e): GEMM directly produces log2-domain scores
static constexpr float QSCALE = 0.125f * 1.44269504088896340736f;

__device__ __forceinline__ unsigned cvt_pk_bf16(float lo, float hi) {
    unsigned r;
    asm("v_cvt_pk_bf16_f32 %0, %1, %2" : "=v"(r) : "v"(lo), "v"(hi));
    return r;
}

// 256 threads = 4 waves = 2 queries x 2 i-halves (R10 skeleton).
// Inner loop: const-offset LDS reads, hoisted zero-C, packed f32 accumulation.
__global__ __launch_bounds__(256, 2) void tritt_fused(
    const float* __restrict__ qg, const float* __restrict__ k1g,
    const float* __restrict__ k2g, const float* __restrict__ v1g,
    const float* __restrict__ v2g, float* __restrict__ outg)
{
    __shared__ unsigned short sK2[S_ * D_];  // 32 KB, bf16 XOR-swizzled
    __shared__ float sPi[2][S_];             // 2 KB  (per-query pi)
    __shared__ float sPjH[4][S_];            // 4 KB  (per-wave pj partials)

    const int tid = threadIdx.x;
    const int qt = blockIdx.x & 127;         // 128 q-tiles of 2
    const int h  = blockIdx.x >> 7;
    const int q0 = qt * 2;

    const float* K1h = k1g + h * (S_ * D_);
    const float* K2h = k2g + h * (S_ * D_);

    // ---- stage K2 (full) as swizzled bf16 ----
    #pragma unroll
    for (int it = 0; it < 16; ++it) {
        const int e4  = tid * 4 + it * 1024;
        const int row = e4 >> 6, d = e4 & 63;
        const int idx = row * 64 + (d ^ ((row & 7) << 3));
        const float4 b = *(const float4*)(K2h + e4);
        uint2 pb; pb.x = cvt_pk_bf16(b.x, b.y); pb.y = cvt_pk_bf16(b.z, b.w);
        *(uint2*)&sK2[idx] = pb;
    }

    const int w     = tid >> 6;
    const int l     = tid & 63;
    const int g     = l >> 4;      // 16-lane group (k-slice g*8..g*8+7)
    const int sub   = l & 15;
    const int q     = w & 1;       // query within tile
    const int ihalf = w >> 1;      // i-half this wave owns
    const int ibase0 = ihalf * 128;

    // Per-lane constant swizzle columns: row % 8 == sub % 8 for every j-tile row
    const int cb0 = (g * 8) ^ ((sub & 7) << 3);
    const int cb1 = (32 + g * 8) ^ ((sub & 7) << 3);
    const unsigned short* pB0 = &sK2[sub * 64 + cb0];
    const unsigned short* pB1 = &sK2[sub * 64 + cb1];

    // Q fragment for this wave's query, from global (pre-scaled)
    float qs[2][8];
    {
        const float* Qrow = qg + (h * S_ + q0 + q) * D_;
        #pragma unroll
        for (int k = 0; k < 2; ++k) {
            const f32x4 a = *(const f32x4*)(Qrow + k * 32 + g * 8);
            const f32x4 b = *(const f32x4*)(Qrow + k * 32 + g * 8 + 4);
            #pragma unroll
            for (int e = 0; e < 4; ++e) {
                qs[k][e]     = a[e] * QSCALE;
                qs[k][4 + e] = b[e] * QSCALE;
            }
        }
    }
    __syncthreads();

    const f32x4 zC = {0.f, 0.f, 0.f, 0.f};   // hoisted MFMA C-operand

    float pjreg[16];
    #pragma unroll
    for (int a = 0; a < 16; ++a) pjreg[a] = 0.f;

    // ---- 4 passes of 2 i-tiles (own 128-row i-half) x full j (256) ----
    for (int pass = 0; pass < 4; ++pass) {
        // A fragments: W[i,d] = K1[i,d]*Qs[d] from GLOBAL K1
        short8 af[2][2];
        #pragma unroll
        for (int t = 0; t < 2; ++t) {
            const int arow = ibase0 + pass * 32 + t * 16 + sub;
            #pragma unroll
            for (int k = 0; k < 2; ++k) {
                const f32x4 a = *(const f32x4*)(K1h + arow * 64 + k * 32 + g * 8);
                const f32x4 b = *(const f32x4*)(K1h + arow * 64 + k * 32 + g * 8 + 4);
                union { unsigned u[4]; short8 s; } pk;
                pk.u[0] = cvt_pk_bf16(a[0] * qs[k][0], a[1] * qs[k][1]);
                pk.u[1] = cvt_pk_bf16(a[2] * qs[k][2], a[3] * qs[k][3]);
                pk.u[2] = cvt_pk_bf16(b[0] * qs[k][4], b[1] * qs[k][5]);
                pk.u[3] = cvt_pk_bf16(b[2] * qs[k][6], b[3] * qs[k][7]);
                af[t][k] = pk.s;
            }
        }

        // pi accumulators as packed pairs: pi2[t][h] = {r=2h, r=2h+1}
        f32x2 pi2[2][2];
        #pragma unroll
        for (int t = 0; t < 2; ++t)
            #pragma unroll
            for (int hh = 0; hh < 2; ++hh) pi2[t][hh] = (f32x2){0.f, 0.f};

        #pragma unroll
        for (int jc = 0; jc < 4; ++jc) {
            #pragma unroll
            for (int jt = 0; jt < 4; ++jt) {
                const int off = jc * 4096 + jt * 1024;    // element offset -> imm
                const short8 b0 = *(const short8*)(pB0 + off);
                const short8 b1 = *(const short8*)(pB1 + off);
                f32x4 acc0 = __builtin_amdgcn_mfma_f32_16x16x32_bf16(af[0][0], b0, zC, 0, 0, 0);
                f32x4 acc1 = __builtin_amdgcn_mfma_f32_16x16x32_bf16(af[1][0], b0, zC, 0, 0, 0);
                acc0 = __builtin_amdgcn_mfma_f32_16x16x32_bf16(af[0][1], b1, acc0, 0, 0, 0);
                acc1 = __builtin_amdgcn_mfma_f32_16x16x32_bf16(af[1][1], b1, acc1, 0, 0, 0);
                // p = 2^t ; packed accumulation (v_pk_add_f32)
                const f32x2 eA = { __builtin_amdgcn_exp2f(acc0[0]), __builtin_amdgcn_exp2f(acc0[1]) };
                const f32x2 eB = { __builtin_amdgcn_exp2f(acc0[2]), __builtin_amdgcn_exp2f(acc0[3]) };
                const f32x2 eC = { __builtin_amdgcn_exp2f(acc1[0]), __builtin_amdgcn_exp2f(acc1[1]) };
                const f32x2 eD = { __builtin_amdgcn_exp2f(acc1[2]), __builtin_amdgcn_exp2f(acc1[3]) };
                pi2[0][0] += eA; pi2[0][1] += eB;
                pi2[1][0] += eC; pi2[1][1] += eD;
                const f32x2 sAB = eA + eB;
                const f32x2 sCD = eC + eD;
                const f32x2 s4  = sAB + sCD;
                pjreg[jc * 4 + jt] += s4[0] + s4[1];      // j = (jc*4+jt)*16 + sub
            }
        }

        // flush pi (reduce over 16 sub lanes = distinct j)
        #pragma unroll
        for (int t = 0; t < 2; ++t)
            #pragma unroll
            for (int hh = 0; hh < 2; ++hh)
                #pragma unroll
                for (int e = 0; e < 2; ++e) {
                    float v = pi2[t][hh][e];
                    v += __shfl_xor(v, 1); v += __shfl_xor(v, 2);
                    v += __shfl_xor(v, 4); v += __shfl_xor(v, 8);
                    if (sub == 0)
                        sPi[q][ibase0 + pass * 32 + t * 16 + g * 4 + hh * 2 + e] = v;
                }
    }

    // pj partials: reduce over the 4 lane-groups (distinct i) -> per-wave strip
    #pragma unroll
    for (int jj = 0; jj < 16; ++jj) {
        float v = pjreg[jj];
        v += __shfl_xor(v, 16); v += __shfl_xor(v, 32);
        if (l < 16) sPjH[w][jj * 16 + l] = v;
    }
    __syncthreads();   // main phase done; sK2 now dead

    // ---- cooperative epilogue: wave w covers rows [w*64, w*64+64) for both q ----
    float* sTmp = (float*)sK2;   // 512 floats carved from dead sK2
    {
        const int d = l;
        const float* V1h = v1g + h * (S_ * D_);
        const float* V2h = v2g + h * (S_ * D_);
        float p0 = 0.f, p1 = 0.f;
        #pragma unroll 4
        for (int rb = 0; rb < 16; ++rb) {
            const int r0 = w * 64 + rb * 4;
            const f32x4 pi0 = *(const f32x4*)&sPi[0][r0];
            const f32x4 pi1 = *(const f32x4*)&sPi[1][r0];
            const f32x4 pa0 = *(const f32x4*)&sPjH[0][r0];
            const f32x4 pa1 = *(const f32x4*)&sPjH[1][r0];
            const f32x4 pa2 = *(const f32x4*)&sPjH[2][r0];
            const f32x4 pa3 = *(const f32x4*)&sPjH[3][r0];
            #pragma unroll
            for (int e = 0; e < 4; ++e) {
                const float v1 = V1h[(r0 + e) * D_ + d];
                const float v2 = V2h[(r0 + e) * D_ + d];
                p0 += pi0[e] * v1 + (pa0[e] + pa2[e]) * v2;
                p1 += pi1[e] * v1 + (pa1[e] + pa3[e]) * v2;
            }
        }
        sTmp[w * 128 + 0 * 64 + d] = p0;
        sTmp[w * 128 + 1 * 64 + d] = p1;
    }
    __syncthreads();
    if (tid < 128) {
        const int qq = tid >> 6, d = tid & 63;
        const float oo = sTmp[0 * 128 + qq * 64 + d] + sTmp[1 * 128 + qq * 64 + d]
                       + sTmp[2 * 128 + qq * 64 + d] + sTmp[3 * 128 + qq * 64 + d];
        float ls = sPi[qq][d] + sPi[qq][64 + d] + sPi[qq][128 + d] + sPi[qq][192 + d];
        ls += __shfl_xor(ls, 1);  ls += __shfl_xor(ls, 2);  ls += __shfl_xor(ls, 4);
        ls += __shfl_xor(ls, 8);  ls += __shfl_xor(ls, 16); ls += __shfl_xor(ls, 32);
        outg[(h * S_ + q0 + qq) * D_ + d] = oo / ls;
        if (d == 0)
            outg[8 * S_ * D_ + h * S_ + q0 + qq] = logf(ls);
    }
}

extern "C" void kernel_launch(void* const* d_in, const int* in_sizes, int n_in,
                              void* d_out, int out_size, void* d_ws, size_t ws_size,
                              hipStream_t stream) {
    const float* q  = (const float*)d_in[0];
    const float* k1 = (const float*)d_in[1];
    const float* k2 = (const float*)d_in[2];
    const float* v1 = (const float*)d_in[3];
    const float* v2 = (const float*)d_in[4];
    float* out = (float*)d_out;
    tritt_fused<<<dim3(8 * (S_ / 2)), dim3(256), 0, stream>>>(q, k1, k2, v1, v2, out);
}